// Round 4
// baseline (271.458 us; speedup 1.0000x reference)
//
#include <hip/hip_runtime.h>

#define NTOK 49
#define NH 6
#define DIM 192
#define QKV_DIM 576
#define PI_F 3.14159265358979323846f
#define LOG2E_F 1.44269504088896340736f

typedef __bf16 bf16_t;
typedef __bf16 bf16x4 __attribute__((ext_vector_type(4)));
typedef __bf16 bf16x8 __attribute__((ext_vector_type(8)));
typedef float f32x4 __attribute__((ext_vector_type(4)));
typedef short s16x4 __attribute__((ext_vector_type(4)));

// ---------------- Kernel 0: convert weights fp32 -> bf16 ----------------
// Q-rows (first DIM rows of qkv_w) get pre-scaled by 32^-0.5 * log2(e) so the
// attention exp becomes a bare exp2 and the q-pack needs no muls.
__global__ __launch_bounds__(256) void cvt_weights(const float* __restrict__ qkv_w,
                                                   const float* __restrict__ proj_w,
                                                   bf16_t* __restrict__ wq,
                                                   bf16_t* __restrict__ wp) {
    const float qscale = 0.17677669529663687f * LOG2E_F;
    int idx = blockIdx.x * 256 + threadIdx.x;
    if (idx < QKV_DIM * DIM) {
        float v = qkv_w[idx];
        if (idx < DIM * DIM) v *= qscale;
        wq[idx] = (bf16_t)v;
    } else {
        int j = idx - QKV_DIM * DIM;
        if (j < DIM * DIM) wp[j] = (bf16_t)proj_w[j];
    }
}

// 16B-block XOR swizzle for the x/O LDS tile (stride DIM=192 elems, no pad).
__device__ __forceinline__ int swz(int r, int c) {
    return r * DIM + (((c >> 3) ^ (r & 7)) << 3) + (c & 7);
}

// pack 4 floats -> 4 bf16 viewed as short4 (ready-made 16x16x16 MFMA fragment)
__device__ __forceinline__ s16x4 pack4s(float a, float b, float c, float d) {
    bf16x4 t = { (bf16_t)a, (bf16_t)b, (bf16_t)c, (bf16_t)d };
    union { bf16x4 v; s16x4 s; } u;
    u.v = t;
    return u.s;
}

// ---------------- Kernel 1: fully-fused window attention ----------------
// TWO windows per block (768 thr = 12 waves). Wave w: window wb=w/6, head h=w%6.
// R3 analysis: VALU is the top pipe (26% vs MFMA 14%), half of it in the
// softmax inner loop. This version: no-max softmax (logits provably tiny),
// sentinel-index masking (1 umin replaces clamp+cndmask+fmax), exp2 with
// log2e folded into the q-weights, rcp instead of fdiv.
__global__ __launch_bounds__(768, 3) void fused_win_attn(
        const float* __restrict__ x,
        const float* __restrict__ Dp,
        const bf16_t* __restrict__ wq,
        const float* __restrict__ qkv_b,
        const bf16_t* __restrict__ wp,
        const float* __restrict__ proj_b,
        const float* __restrict__ a_p,
        const float* __restrict__ b_p,
        const float* __restrict__ a_r,
        const float* __restrict__ b_r,
        float* __restrict__ out,
        int nwin) {
    __shared__ __align__(16) bf16_t sh_xo[2][NTOK * DIM];   // x, later O (2 x 18.4 KB)
    __shared__ float bias_sh[12][170];                      // per (window,head); [169] = -1e30

    const int tid  = threadIdx.x;
    const int w    = tid >> 6;        // wave id 0..11
    const int lane = tid & 63;
    const int l16  = lane & 15;
    const int quad = lane >> 4;
    const int wb   = w / 6;           // window sub-slot
    const int h    = w % 6;           // head
    const int win  = blockIdx.x * 2 + wb;
    const int winc = min(win, nwin - 1);
    const bool alive = (win < nwin);

    bf16_t* xl     = sh_xo[wb];
    float*  bias13 = bias_sh[w];

    // ---- Phase 0: stage x for both windows (49x192 fp32 -> bf16 LDS, swizzled) ----
    for (int u = tid; u < 4704; u += 768) {               // 2*49*192/4
        int wbs = (u >= 2352) ? 1 : 0;
        int e = (u - wbs * 2352) * 4;
        int r = e / 192, c = e % 192;
        int wsrc = min(blockIdx.x * 2 + wbs, nwin - 1);
        float4 xv = *(const float4*)(x + (size_t)wsrc * (NTOK * DIM) + e);
        bf16x4 pk = { (bf16_t)xv.x, (bf16_t)xv.y, (bf16_t)xv.z, (bf16_t)xv.w };
        *(bf16x4*)(&sh_xo[wbs][swz(r, c)]) = pk;
    }

    // ---- bias table (pre-scaled by log2e; entry 169 = -1e30 sentinel) ----
    const float Dv = Dp[winc];
    for (int u = lane; u < 170; u += 64) {
        if (u == 169) {
            bias13[u] = -1e30f;
        } else {
            int dr = u / 13 - 6, da = u % 13 - 6;
            int ri = (dr < 0) ? dr + 13 : dr;
            int ai = (da < 0) ? da + 13 : da;
            float ang_a = (float)da * (2.0f * PI_F / 56.0f);
            float ang_r = Dv * (float)dr * (2.0f * PI_F / 448.0f);
            bias13[u] = LOG2E_F *
                (a_p[ai * NH + h] * __cosf(ang_a) + b_p[ai * NH + h] * __sinf(ang_a)
               + a_r[ri * NH + h] * __cosf(ang_r) + b_r[ri * NH + h] * __sinf(ang_r));
        }
    }
    __syncthreads();

    // clamped token rows for fragment reads (rows >=49 clamp to 48, masked later)
    int rowc[4];
#pragma unroll
    for (int mt = 0; mt < 4; ++mt)
        rowc[mt] = min(mt * 16 + l16, 48);

    // ---- Phase 1: merged Q/K/V gemms (single pass over x fragments) ----
    // Q,K swapped order (W as A): D = [channel rows in-lane][token col = l16]
    // V standard order (x as A):  D = [token rows in-lane][channel col = l16]
    s16x4 qp[4][2], kp[4][2], vp[4][2];
    {
        const bf16_t* wgq = wq + (size_t)(h * 32) * DIM;
        const bf16_t* wgk = wq + (size_t)(DIM + h * 32) * DIM;
        const bf16_t* wgv = wq + (size_t)(2 * DIM + h * 32) * DIM;
        f32x4 qa[4][2] = {}, ka[4][2] = {}, va[4][2] = {};
#pragma unroll
        for (int ks = 0; ks < 6; ++ks) {
            bf16x8 wq0 = *(const bf16x8*)(wgq + (size_t)l16 * DIM + ks * 32 + quad * 8);
            bf16x8 wq1 = *(const bf16x8*)(wgq + (size_t)(16 + l16) * DIM + ks * 32 + quad * 8);
            bf16x8 wk0 = *(const bf16x8*)(wgk + (size_t)l16 * DIM + ks * 32 + quad * 8);
            bf16x8 wk1 = *(const bf16x8*)(wgk + (size_t)(16 + l16) * DIM + ks * 32 + quad * 8);
            bf16x8 wv0 = *(const bf16x8*)(wgv + (size_t)l16 * DIM + ks * 32 + quad * 8);
            bf16x8 wv1 = *(const bf16x8*)(wgv + (size_t)(16 + l16) * DIM + ks * 32 + quad * 8);
#pragma unroll
            for (int mt = 0; mt < 4; ++mt) {
                bf16x8 xf = *(const bf16x8*)(&xl[swz(rowc[mt], ks * 32 + quad * 8)]);
                qa[mt][0] = __builtin_amdgcn_mfma_f32_16x16x32_bf16(wq0, xf, qa[mt][0], 0, 0, 0);
                qa[mt][1] = __builtin_amdgcn_mfma_f32_16x16x32_bf16(wq1, xf, qa[mt][1], 0, 0, 0);
                ka[mt][0] = __builtin_amdgcn_mfma_f32_16x16x32_bf16(wk0, xf, ka[mt][0], 0, 0, 0);
                ka[mt][1] = __builtin_amdgcn_mfma_f32_16x16x32_bf16(wk1, xf, ka[mt][1], 0, 0, 0);
                va[mt][0] = __builtin_amdgcn_mfma_f32_16x16x32_bf16(xf, wv0, va[mt][0], 0, 0, 0);
                va[mt][1] = __builtin_amdgcn_mfma_f32_16x16x32_bf16(xf, wv1, va[mt][1], 0, 0, 0);
            }
        }
        const float qbs = 0.17677669529663687f * LOG2E_F;
        float4 bq0 = *(const float4*)(qkv_b + h * 32 + quad * 4);
        float4 bq1 = *(const float4*)(qkv_b + h * 32 + 16 + quad * 4);
        float4 bk0 = *(const float4*)(qkv_b + DIM + h * 32 + quad * 4);
        float4 bk1 = *(const float4*)(qkv_b + DIM + h * 32 + 16 + quad * 4);
        float bv0 = qkv_b[2 * DIM + h * 32 + l16];
        float bv1 = qkv_b[2 * DIM + h * 32 + 16 + l16];
#pragma unroll
        for (int mt = 0; mt < 4; ++mt) {
            // qp/kp[token-tile][d-half]: lane holds [d=quad*4+r][tok=l16]
            qp[mt][0] = pack4s(qa[mt][0][0] + bq0.x * qbs, qa[mt][0][1] + bq0.y * qbs,
                               qa[mt][0][2] + bq0.z * qbs, qa[mt][0][3] + bq0.w * qbs);
            qp[mt][1] = pack4s(qa[mt][1][0] + bq1.x * qbs, qa[mt][1][1] + bq1.y * qbs,
                               qa[mt][1][2] + bq1.z * qbs, qa[mt][1][3] + bq1.w * qbs);
            kp[mt][0] = pack4s(ka[mt][0][0] + bk0.x, ka[mt][0][1] + bk0.y,
                               ka[mt][0][2] + bk0.z, ka[mt][0][3] + bk0.w);
            kp[mt][1] = pack4s(ka[mt][1][0] + bk1.x, ka[mt][1][1] + bk1.y,
                               ka[mt][1][2] + bk1.z, ka[mt][1][3] + bk1.w);
            // vp[token-tile][d-half]: V^T A-frag, lane holds [d=l16][tok=quad*4+r]
            vp[mt][0] = pack4s(va[mt][0][0] + bv0, va[mt][0][1] + bv0,
                               va[mt][0][2] + bv0, va[mt][0][3] + bv0);
            vp[mt][1] = pack4s(va[mt][1][0] + bv1, va[mt][1][1] + bv1,
                               va[mt][1][2] + bv1, va[mt][1][3] + bv1);
        }
    }

    // per-lane j-codes: j = nt*16+quad*4+r; invalid j (>=49) -> sentinel 240 so
    // idx = icode - jc goes negative -> umin clamps to 169 -> bias = -1e30 -> exp2 = 0
    int jcp[4];
#pragma unroll
    for (int nt = 0; nt < 4; ++nt) {
        int p = 0;
#pragma unroll
        for (int r = 0; r < 4; ++r) {
            int j = nt * 16 + quad * 4 + r;
            int code = (j < 49) ? ((j / 7) * 13 + (j % 7)) : 240;
            p |= code << (8 * r);
        }
        jcp[nt] = p;
    }

    // hoist proj weights early (VMEM latency overlaps attention compute)
    bf16x8 wf[2][6];
#pragma unroll
    for (int nt = 0; nt < 2; ++nt)
#pragma unroll
        for (int ks = 0; ks < 6; ++ks)
            wf[nt][ks] = *(const bf16x8*)(wp + (size_t)(h * 32 + nt * 16 + l16) * DIM + ks * 32 + quad * 8);

    __syncthreads();   // all waves done reading x from sh_xo; O may now overwrite

    // ---- Phase 2: attention via 16x16x16 MFMA; no-max exp2 softmax ----
    // S^T tile = mfma16(K-frag, Q-frag): S^T[j=nt*16+quad*4+r][i=mt*16+l16]
#pragma unroll
    for (int mt = 0; mt < 4; ++mt) {
        f32x4 s[4] = {};
#pragma unroll
        for (int nt = 0; nt < 4; ++nt) {
            s[nt] = __builtin_amdgcn_mfma_f32_16x16x16bf16_1k(kp[nt][0], qp[mt][0], s[nt], 0, 0, 0);
            s[nt] = __builtin_amdgcn_mfma_f32_16x16x16bf16_1k(kp[nt][1], qp[mt][1], s[nt], 0, 0, 0);
        }

        int i = mt * 16 + l16;
        int icl = min(i, 48);
        int icode = (icl / 7) * 13 + (icl % 7) + 84;

        float ev[4][4];
        float sum = 0.f;
#pragma unroll
        for (int nt = 0; nt < 4; ++nt)
#pragma unroll
            for (int r = 0; r < 4; ++r) {
                unsigned idx = (unsigned)(icode - ((jcp[nt] >> (8 * r)) & 255));
                idx = min(idx, 169u);
                float e = exp2f(s[nt][r] + bias13[idx]);
                ev[nt][r] = e;
                sum += e;
            }
        sum += __shfl_xor(sum, 16);
        sum += __shfl_xor(sum, 32);
        float rs = __builtin_amdgcn_rcpf(sum);

        // P^T B-frags are just the packed evs: [k=j=kt*16+quad*4+r][col=i=l16]
        s16x4 pvs[4];
#pragma unroll
        for (int nt = 0; nt < 4; ++nt)
            pvs[nt] = pack4s(ev[nt][0], ev[nt][1], ev[nt][2], ev[nt][3]);

        // O^T = V^T * P^T : D[d=quad*4+r (within ntd half)][i=l16]
        f32x4 o0 = {}, o1 = {};
#pragma unroll
        for (int kt = 0; kt < 4; ++kt) {
            o0 = __builtin_amdgcn_mfma_f32_16x16x16bf16_1k(vp[kt][0], pvs[kt], o0, 0, 0, 0);
            o1 = __builtin_amdgcn_mfma_f32_16x16x16bf16_1k(vp[kt][1], pvs[kt], o1, 0, 0, 0);
        }

        if (i < 49) {
            *(s16x4*)(&xl[swz(i, h * 32 + quad * 4)]) =
                pack4s(o0[0] * rs, o0[1] * rs, o0[2] * rs, o0[3] * rs);
            *(s16x4*)(&xl[swz(i, h * 32 + 16 + quad * 4)]) =
                pack4s(o1[0] * rs, o1[1] * rs, o1[2] * rs, o1[3] * rs);
        }
    }

    __syncthreads();   // all heads' O written into sh_xo

    // ---- Phase 3: output projection; wave w covers out channels [h*32, h*32+32) ----
    f32x4 pacc[4][2] = {};
#pragma unroll
    for (int mt = 0; mt < 4; ++mt)
#pragma unroll
        for (int ks = 0; ks < 6; ++ks) {
            bf16x8 oa = *(const bf16x8*)(&xl[swz(rowc[mt], ks * 32 + quad * 8)]);
            pacc[mt][0] = __builtin_amdgcn_mfma_f32_16x16x32_bf16(oa, wf[0][ks], pacc[mt][0], 0, 0, 0);
            pacc[mt][1] = __builtin_amdgcn_mfma_f32_16x16x32_bf16(oa, wf[1][ks], pacc[mt][1], 0, 0, 0);
        }

    float pb0 = proj_b[h * 32 + l16];
    float pb1 = proj_b[h * 32 + 16 + l16];
#pragma unroll
    for (int mt = 0; mt < 4; ++mt)
#pragma unroll
        for (int r = 0; r < 4; ++r) {
            int i = mt * 16 + quad * 4 + r;
            if (alive && i < 49) {
                float* op = out + ((size_t)win * NTOK + i) * DIM + h * 32;
                op[l16]      = pacc[mt][0][r] + pb0;
                op[16 + l16] = pacc[mt][1][r] + pb1;
            }
        }
}

extern "C" void kernel_launch(void* const* d_in, const int* in_sizes, int n_in,
                              void* d_out, int out_size, void* d_ws, size_t ws_size,
                              hipStream_t stream) {
    const float* x      = (const float*)d_in[0];
    const float* D      = (const float*)d_in[1];
    const float* qkv_w  = (const float*)d_in[2];
    const float* qkv_b  = (const float*)d_in[3];
    const float* proj_w = (const float*)d_in[4];
    const float* proj_b = (const float*)d_in[5];
    const float* a_p    = (const float*)d_in[6];
    const float* b_p    = (const float*)d_in[7];
    const float* a_r    = (const float*)d_in[8];
    const float* b_r    = (const float*)d_in[9];
    float* out = (float*)d_out;

    const int B_ = in_sizes[0] / (NTOK * DIM);   // 2048 windows

    char* wsp = (char*)d_ws;
    bf16_t* wq = (bf16_t*)wsp; wsp += (size_t)QKV_DIM * DIM * 2;
    bf16_t* wp = (bf16_t*)wsp;

    cvt_weights<<<dim3((QKV_DIM * DIM + DIM * DIM + 255) / 256), dim3(256), 0, stream>>>(
        qkv_w, proj_w, wq, wp);

    fused_win_attn<<<dim3((B_ + 1) / 2), dim3(768), 0, stream>>>(
        x, D, wq, qkv_b, wp, proj_b, a_p, b_p, a_r, b_r, out, B_);
}

// Round 5
// 263.652 us; speedup vs baseline: 1.0296x; 1.0296x over previous
//
#include <hip/hip_runtime.h>

#define NTOK 49
#define NH 6
#define DIM 192
#define QKV_DIM 576
#define PI_F 3.14159265358979323846f
#define LOG2E_F 1.44269504088896340736f

typedef __bf16 bf16_t;
typedef __bf16 bf16x4 __attribute__((ext_vector_type(4)));
typedef __bf16 bf16x8 __attribute__((ext_vector_type(8)));
typedef float f32x4 __attribute__((ext_vector_type(4)));
typedef short s16x4 __attribute__((ext_vector_type(4)));

// ---------------- Kernel 0: convert weights fp32 -> bf16 ----------------
// Q-rows (first DIM rows of qkv_w) get pre-scaled by 32^-0.5 * log2(e) so the
// attention exp becomes a bare v_exp_f32 and the q-pack needs no muls.
__global__ __launch_bounds__(256) void cvt_weights(const float* __restrict__ qkv_w,
                                                   const float* __restrict__ proj_w,
                                                   bf16_t* __restrict__ wq,
                                                   bf16_t* __restrict__ wp) {
    const float qscale = 0.17677669529663687f * LOG2E_F;
    int idx = blockIdx.x * 256 + threadIdx.x;
    if (idx < QKV_DIM * DIM) {
        float v = qkv_w[idx];
        if (idx < DIM * DIM) v *= qscale;
        wq[idx] = (bf16_t)v;
    } else {
        int j = idx - QKV_DIM * DIM;
        if (j < DIM * DIM) wp[j] = (bf16_t)proj_w[j];
    }
}

// 16B-block XOR swizzle for the x/O LDS tile (stride DIM=192 elems, no pad).
__device__ __forceinline__ int swz(int r, int c) {
    return r * DIM + (((c >> 3) ^ (r & 7)) << 3) + (c & 7);
}

// pack 4 floats -> 4 bf16 viewed as short4 (ready-made 16x16x16 MFMA fragment)
__device__ __forceinline__ s16x4 pack4s(float a, float b, float c, float d) {
    bf16x4 t = { (bf16_t)a, (bf16_t)b, (bf16_t)c, (bf16_t)d };
    union { bf16x4 v; s16x4 s; } u;
    u.v = t;
    return u.s;
}

// ---------------- Kernel 1: fully-fused window attention ----------------
// TWO windows per block (768 thr = 12 waves). Wave w: window wb=w/6, head h=w%6.
// R4 post-mortem: exp2f() took the OCML slow path (~10 VALU/call) — this uses
// __builtin_amdgcn_exp2f (exactly one v_exp_f32); mt loop kept rolled (the R4
// unroll perturbed scheduling). Rest as R4: no-max softmax (logits provably
// tiny), sentinel-index masking, log2e folded into q-weights/bias, rcp.
__global__ __launch_bounds__(768, 3) void fused_win_attn(
        const float* __restrict__ x,
        const float* __restrict__ Dp,
        const bf16_t* __restrict__ wq,
        const float* __restrict__ qkv_b,
        const bf16_t* __restrict__ wp,
        const float* __restrict__ proj_b,
        const float* __restrict__ a_p,
        const float* __restrict__ b_p,
        const float* __restrict__ a_r,
        const float* __restrict__ b_r,
        float* __restrict__ out,
        int nwin) {
    __shared__ __align__(16) bf16_t sh_xo[2][NTOK * DIM];   // x, later O (2 x 18.4 KB)
    __shared__ float bias_sh[12][170];                      // per (window,head); [169] = -1e30

    const int tid  = threadIdx.x;
    const int w    = tid >> 6;        // wave id 0..11
    const int lane = tid & 63;
    const int l16  = lane & 15;
    const int quad = lane >> 4;
    const int wb   = w / 6;           // window sub-slot
    const int h    = w % 6;           // head
    const int win  = blockIdx.x * 2 + wb;
    const int winc = min(win, nwin - 1);
    const bool alive = (win < nwin);

    bf16_t* xl     = sh_xo[wb];
    float*  bias13 = bias_sh[w];

    // ---- Phase 0: stage x for both windows (49x192 fp32 -> bf16 LDS, swizzled) ----
    for (int u = tid; u < 4704; u += 768) {               // 2*49*192/4
        int wbs = (u >= 2352) ? 1 : 0;
        int e = (u - wbs * 2352) * 4;
        int r = e / 192, c = e % 192;
        int wsrc = min(blockIdx.x * 2 + wbs, nwin - 1);
        float4 xv = *(const float4*)(x + (size_t)wsrc * (NTOK * DIM) + e);
        bf16x4 pk = { (bf16_t)xv.x, (bf16_t)xv.y, (bf16_t)xv.z, (bf16_t)xv.w };
        *(bf16x4*)(&sh_xo[wbs][swz(r, c)]) = pk;
    }

    // ---- bias table (pre-scaled by log2e; entry 169 = -1e30 sentinel) ----
    const float Dv = Dp[winc];
    for (int u = lane; u < 170; u += 64) {
        if (u == 169) {
            bias13[u] = -1e30f;
        } else {
            int dr = u / 13 - 6, da = u % 13 - 6;
            int ri = (dr < 0) ? dr + 13 : dr;
            int ai = (da < 0) ? da + 13 : da;
            float ang_a = (float)da * (2.0f * PI_F / 56.0f);
            float ang_r = Dv * (float)dr * (2.0f * PI_F / 448.0f);
            bias13[u] = LOG2E_F *
                (a_p[ai * NH + h] * __cosf(ang_a) + b_p[ai * NH + h] * __sinf(ang_a)
               + a_r[ri * NH + h] * __cosf(ang_r) + b_r[ri * NH + h] * __sinf(ang_r));
        }
    }
    __syncthreads();

    // clamped token rows for fragment reads (rows >=49 clamp to 48, masked later)
    int rowc[4];
#pragma unroll
    for (int mt = 0; mt < 4; ++mt)
        rowc[mt] = min(mt * 16 + l16, 48);

    // ---- Phase 1: merged Q/K/V gemms (single pass over x fragments) ----
    // Q,K swapped order (W as A): D = [channel rows in-lane][token col = l16]
    // V standard order (x as A):  D = [token rows in-lane][channel col = l16]
    s16x4 qp[4][2], kp[4][2], vp[4][2];
    {
        const bf16_t* wgq = wq + (size_t)(h * 32) * DIM;
        const bf16_t* wgk = wq + (size_t)(DIM + h * 32) * DIM;
        const bf16_t* wgv = wq + (size_t)(2 * DIM + h * 32) * DIM;
        f32x4 qa[4][2] = {}, ka[4][2] = {}, va[4][2] = {};
#pragma unroll
        for (int ks = 0; ks < 6; ++ks) {
            bf16x8 wq0 = *(const bf16x8*)(wgq + (size_t)l16 * DIM + ks * 32 + quad * 8);
            bf16x8 wq1 = *(const bf16x8*)(wgq + (size_t)(16 + l16) * DIM + ks * 32 + quad * 8);
            bf16x8 wk0 = *(const bf16x8*)(wgk + (size_t)l16 * DIM + ks * 32 + quad * 8);
            bf16x8 wk1 = *(const bf16x8*)(wgk + (size_t)(16 + l16) * DIM + ks * 32 + quad * 8);
            bf16x8 wv0 = *(const bf16x8*)(wgv + (size_t)l16 * DIM + ks * 32 + quad * 8);
            bf16x8 wv1 = *(const bf16x8*)(wgv + (size_t)(16 + l16) * DIM + ks * 32 + quad * 8);
#pragma unroll
            for (int mt = 0; mt < 4; ++mt) {
                bf16x8 xf = *(const bf16x8*)(&xl[swz(rowc[mt], ks * 32 + quad * 8)]);
                qa[mt][0] = __builtin_amdgcn_mfma_f32_16x16x32_bf16(wq0, xf, qa[mt][0], 0, 0, 0);
                qa[mt][1] = __builtin_amdgcn_mfma_f32_16x16x32_bf16(wq1, xf, qa[mt][1], 0, 0, 0);
                ka[mt][0] = __builtin_amdgcn_mfma_f32_16x16x32_bf16(wk0, xf, ka[mt][0], 0, 0, 0);
                ka[mt][1] = __builtin_amdgcn_mfma_f32_16x16x32_bf16(wk1, xf, ka[mt][1], 0, 0, 0);
                va[mt][0] = __builtin_amdgcn_mfma_f32_16x16x32_bf16(xf, wv0, va[mt][0], 0, 0, 0);
                va[mt][1] = __builtin_amdgcn_mfma_f32_16x16x32_bf16(xf, wv1, va[mt][1], 0, 0, 0);
            }
        }
        const float qbs = 0.17677669529663687f * LOG2E_F;
        float4 bq0 = *(const float4*)(qkv_b + h * 32 + quad * 4);
        float4 bq1 = *(const float4*)(qkv_b + h * 32 + 16 + quad * 4);
        float4 bk0 = *(const float4*)(qkv_b + DIM + h * 32 + quad * 4);
        float4 bk1 = *(const float4*)(qkv_b + DIM + h * 32 + 16 + quad * 4);
        float bv0 = qkv_b[2 * DIM + h * 32 + l16];
        float bv1 = qkv_b[2 * DIM + h * 32 + 16 + l16];
        float bq0x = bq0.x * qbs, bq0y = bq0.y * qbs, bq0z = bq0.z * qbs, bq0w = bq0.w * qbs;
        float bq1x = bq1.x * qbs, bq1y = bq1.y * qbs, bq1z = bq1.z * qbs, bq1w = bq1.w * qbs;
#pragma unroll
        for (int mt = 0; mt < 4; ++mt) {
            // qp/kp[token-tile][d-half]: lane holds [d=quad*4+r][tok=l16]
            qp[mt][0] = pack4s(qa[mt][0][0] + bq0x, qa[mt][0][1] + bq0y,
                               qa[mt][0][2] + bq0z, qa[mt][0][3] + bq0w);
            qp[mt][1] = pack4s(qa[mt][1][0] + bq1x, qa[mt][1][1] + bq1y,
                               qa[mt][1][2] + bq1z, qa[mt][1][3] + bq1w);
            kp[mt][0] = pack4s(ka[mt][0][0] + bk0.x, ka[mt][0][1] + bk0.y,
                               ka[mt][0][2] + bk0.z, ka[mt][0][3] + bk0.w);
            kp[mt][1] = pack4s(ka[mt][1][0] + bk1.x, ka[mt][1][1] + bk1.y,
                               ka[mt][1][2] + bk1.z, ka[mt][1][3] + bk1.w);
            // vp[token-tile][d-half]: V^T A-frag, lane holds [d=l16][tok=quad*4+r]
            vp[mt][0] = pack4s(va[mt][0][0] + bv0, va[mt][0][1] + bv0,
                               va[mt][0][2] + bv0, va[mt][0][3] + bv0);
            vp[mt][1] = pack4s(va[mt][1][0] + bv1, va[mt][1][1] + bv1,
                               va[mt][1][2] + bv1, va[mt][1][3] + bv1);
        }
    }

    // per-lane j-codes: j = nt*16+quad*4+r; invalid j (>=49) -> sentinel 240 so
    // idx = icode - jc goes negative -> umin clamps to 169 -> bias = -1e30 -> exp2 = 0
    int jcp[4];
#pragma unroll
    for (int nt = 0; nt < 4; ++nt) {
        int p = 0;
#pragma unroll
        for (int r = 0; r < 4; ++r) {
            int j = nt * 16 + quad * 4 + r;
            int code = (j < 49) ? ((j / 7) * 13 + (j % 7)) : 240;
            p |= code << (8 * r);
        }
        jcp[nt] = p;
    }

    // hoist proj weights early (VMEM latency overlaps attention compute)
    bf16x8 wf[2][6];
#pragma unroll
    for (int nt = 0; nt < 2; ++nt)
#pragma unroll
        for (int ks = 0; ks < 6; ++ks)
            wf[nt][ks] = *(const bf16x8*)(wp + (size_t)(h * 32 + nt * 16 + l16) * DIM + ks * 32 + quad * 8);

    __syncthreads();   // all waves done reading x from sh_xo; O may now overwrite

    // ---- Phase 2: attention via 16x16x16 MFMA; no-max v_exp softmax ----
    // S^T tile = mfma16(K-frag, Q-frag): S^T[j=nt*16+quad*4+r][i=mt*16+l16]
    for (int mt = 0; mt < 4; ++mt) {
        f32x4 s[4] = {};
#pragma unroll
        for (int nt = 0; nt < 4; ++nt) {
            s[nt] = __builtin_amdgcn_mfma_f32_16x16x16bf16_1k(kp[nt][0], qp[mt][0], s[nt], 0, 0, 0);
            s[nt] = __builtin_amdgcn_mfma_f32_16x16x16bf16_1k(kp[nt][1], qp[mt][1], s[nt], 0, 0, 0);
        }

        int i = mt * 16 + l16;
        int icl = min(i, 48);
        int icode = (icl / 7) * 13 + (icl % 7) + 84;

        float ev[4][4];
        float sum = 0.f;
#pragma unroll
        for (int nt = 0; nt < 4; ++nt)
#pragma unroll
            for (int r = 0; r < 4; ++r) {
                unsigned idx = (unsigned)(icode - ((jcp[nt] >> (8 * r)) & 255));
                idx = min(idx, 169u);
                float e = __builtin_amdgcn_exp2f(s[nt][r] + bias13[idx]);
                ev[nt][r] = e;
                sum += e;
            }
        sum += __shfl_xor(sum, 16);
        sum += __shfl_xor(sum, 32);
        float rs = __builtin_amdgcn_rcpf(sum);

        // P^T B-frags are just the packed evs: [k=j=kt*16+quad*4+r][col=i=l16]
        s16x4 pvs[4];
#pragma unroll
        for (int nt = 0; nt < 4; ++nt)
            pvs[nt] = pack4s(ev[nt][0], ev[nt][1], ev[nt][2], ev[nt][3]);

        // O^T = V^T * P^T : D[d=quad*4+r (within ntd half)][i=l16]
        f32x4 o0 = {}, o1 = {};
#pragma unroll
        for (int kt = 0; kt < 4; ++kt) {
            o0 = __builtin_amdgcn_mfma_f32_16x16x16bf16_1k(vp[kt][0], pvs[kt], o0, 0, 0, 0);
            o1 = __builtin_amdgcn_mfma_f32_16x16x16bf16_1k(vp[kt][1], pvs[kt], o1, 0, 0, 0);
        }

        if (i < 49) {
            *(s16x4*)(&xl[swz(i, h * 32 + quad * 4)]) =
                pack4s(o0[0] * rs, o0[1] * rs, o0[2] * rs, o0[3] * rs);
            *(s16x4*)(&xl[swz(i, h * 32 + 16 + quad * 4)]) =
                pack4s(o1[0] * rs, o1[1] * rs, o1[2] * rs, o1[3] * rs);
        }
    }

    __syncthreads();   // all heads' O written into sh_xo

    // ---- Phase 3: output projection; wave w covers out channels [h*32, h*32+32) ----
    f32x4 pacc[4][2] = {};
#pragma unroll
    for (int mt = 0; mt < 4; ++mt)
#pragma unroll
        for (int ks = 0; ks < 6; ++ks) {
            bf16x8 oa = *(const bf16x8*)(&xl[swz(rowc[mt], ks * 32 + quad * 8)]);
            pacc[mt][0] = __builtin_amdgcn_mfma_f32_16x16x32_bf16(oa, wf[0][ks], pacc[mt][0], 0, 0, 0);
            pacc[mt][1] = __builtin_amdgcn_mfma_f32_16x16x32_bf16(oa, wf[1][ks], pacc[mt][1], 0, 0, 0);
        }

    float pb0 = proj_b[h * 32 + l16];
    float pb1 = proj_b[h * 32 + 16 + l16];
#pragma unroll
    for (int mt = 0; mt < 4; ++mt)
#pragma unroll
        for (int r = 0; r < 4; ++r) {
            int i = mt * 16 + quad * 4 + r;
            if (alive && i < 49) {
                float* op = out + ((size_t)win * NTOK + i) * DIM + h * 32;
                op[l16]      = pacc[mt][0][r] + pb0;
                op[16 + l16] = pacc[mt][1][r] + pb1;
            }
        }
}

extern "C" void kernel_launch(void* const* d_in, const int* in_sizes, int n_in,
                              void* d_out, int out_size, void* d_ws, size_t ws_size,
                              hipStream_t stream) {
    const float* x      = (const float*)d_in[0];
    const float* D      = (const float*)d_in[1];
    const float* qkv_w  = (const float*)d_in[2];
    const float* qkv_b  = (const float*)d_in[3];
    const float* proj_w = (const float*)d_in[4];
    const float* proj_b = (const float*)d_in[5];
    const float* a_p    = (const float*)d_in[6];
    const float* b_p    = (const float*)d_in[7];
    const float* a_r    = (const float*)d_in[8];
    const float* b_r    = (const float*)d_in[9];
    float* out = (float*)d_out;

    const int B_ = in_sizes[0] / (NTOK * DIM);   // 2048 windows

    char* wsp = (char*)d_ws;
    bf16_t* wq = (bf16_t*)wsp; wsp += (size_t)QKV_DIM * DIM * 2;
    bf16_t* wp = (bf16_t*)wsp;

    cvt_weights<<<dim3((QKV_DIM * DIM + DIM * DIM + 255) / 256), dim3(256), 0, stream>>>(
        qkv_w, proj_w, wq, wp);

    fused_win_attn<<<dim3((B_ + 1) / 2), dim3(768), 0, stream>>>(
        x, D, wq, qkv_b, wp, proj_b, a_p, b_p, a_r, b_r, out, B_);
}